// Round 1
// baseline (397.943 us; speedup 1.0000x reference)
//
#include <hip/hip_runtime.h>
#include <math.h>

#define NPTS 4096
#define NB   8
#define NC   64
#define KSEL 30
#define NROWS (NB * NPTS * KSEL)   // 983040
#define CNT_F 983040.0f

static __device__ __forceinline__ unsigned long long shfl_xor_u64(unsigned long long v, int lx) {
    int lo = __shfl_xor((int)(unsigned)(v & 0xFFFFFFFFULL), lx, 64);
    int hi = __shfl_xor((int)(unsigned)(v >> 32), lx, 64);
    return ((unsigned long long)(unsigned)hi << 32) | (unsigned)lo;
}

// ---------------------------------------------------------------------------
// Kernel 1: exact KNN (top-30 by pd = 2*dot - xx_n - xx_m, ties -> lower idx)
// one wave per query; block = 4 waves = 4 queries; blockIdx.y = batch
// ---------------------------------------------------------------------------
__global__ __launch_bounds__(256) void knn_k(const float* __restrict__ xloc,
                                             int* __restrict__ idx_out) {
    __shared__ float sx[NPTS], sy[NPTS], sz[NPTS];
    __shared__ unsigned long long surv[4][256];

    const int b    = blockIdx.y;
    const int tid  = threadIdx.x;
    const int lane = tid & 63;
    const int wv   = tid >> 6;
    const int n    = (blockIdx.x << 2) + wv;

    const float* xb = xloc + (size_t)b * (3 * NPTS);
    for (int i = tid; i < NPTS; i += 256) {
        sx[i] = xb[i];
        sy[i] = xb[NPTS + i];
        sz[i] = xb[2 * NPTS + i];
    }
    __syncthreads();

    const float qx = sx[n], qy = sy[n], qz = sz[n];
    const float qxx = __fadd_rn(__fadd_rn(__fmul_rn(qx, qx), __fmul_rn(qy, qy)), __fmul_rn(qz, qz));

    // distances -> ordered-uint keys, 64 per lane (candidate j = lane + 64*t)
    unsigned K[64];
#pragma unroll
    for (int t = 0; t < 64; ++t) {
        const int j = lane + (t << 6);
        const float cx = sx[j], cy = sy[j], cz = sz[j];
        const float cxx = __fadd_rn(__fadd_rn(__fmul_rn(cx, cx), __fmul_rn(cy, cy)), __fmul_rn(cz, cz));
        const float dt  = __fadd_rn(__fadd_rn(__fmul_rn(qx, cx), __fmul_rn(qy, cy)), __fmul_rn(qz, cz));
        const float pd  = __fsub_rn(__fsub_rn(__fmul_rn(2.0f, dt), qxx), cxx);
        const unsigned u = __float_as_uint(pd);
        K[t] = u ^ ((unsigned)((int)u >> 31) | 0x80000000u);
    }

    // per-lane max
    unsigned lm = 0;
#pragma unroll
    for (int t = 0; t < 64; ++t) lm = (K[t] > lm) ? K[t] : lm;

    // bitonic sort of 64 lane-maxima (descending); tau = 31st largest
    unsigned v = lm;
#pragma unroll
    for (int k = 2; k <= 64; k <<= 1) {
#pragma unroll
        for (int j = k >> 1; j > 0; j >>= 1) {
            unsigned o = (unsigned)__shfl_xor((int)v, j, 64);
            const bool lower = (lane & j) == 0;
            const bool desc  = (lane & k) == 0;
            const unsigned mx = v > o ? v : o;
            const unsigned mn = v > o ? o : v;
            v = (lower == desc) ? mx : mn;
        }
    }
    const unsigned tau = (unsigned)__shfl((int)v, 30, 64);

    // ballot compaction of survivors (key >= tau); guaranteed >= 31 of them
    unsigned total = 0;
#pragma unroll
    for (int t = 0; t < 64; ++t) {
        const bool p = (K[t] >= tau);
        const unsigned long long m = __ballot(p);
        if (p) {
            const unsigned pos = total + (unsigned)__popcll(m & ((1ULL << lane) - 1ULL));
            if (pos < 256u) {
                const unsigned j = (unsigned)(lane + (t << 6));
                surv[wv][pos] = ((unsigned long long)K[t] << 32) | (unsigned)(~j);
            }
        }
        total += (unsigned)__popcll(m);
    }
    if (total <= 256u) {
        for (unsigned i = total + (unsigned)lane; i < 256u; i += 64u) surv[wv][i] = 0ULL;
    }
    __syncthreads();

    const size_t obase = ((size_t)(b * NPTS + n)) * KSEL;

    if (total <= 256u) {
        // bitonic sort 256 packed keys (descending), 4 elements/lane, e = 4*lane + r
        unsigned long long S[4];
#pragma unroll
        for (int r = 0; r < 4; ++r) S[r] = surv[wv][4 * lane + r];

#pragma unroll
        for (int k = 2; k <= 256; k <<= 1) {
#pragma unroll
            for (int j = k >> 1; j > 0; j >>= 1) {
                if (j >= 4) {
                    const int lx = j >> 2;
#pragma unroll
                    for (int r = 0; r < 4; ++r) {
                        const unsigned long long o = shfl_xor_u64(S[r], lx);
                        const int e = 4 * lane + r;
                        const bool lower = (e & j) == 0;
                        const bool desc  = (e & k) == 0;
                        const unsigned long long mx = S[r] > o ? S[r] : o;
                        const unsigned long long mn = S[r] > o ? o : S[r];
                        S[r] = (lower == desc) ? mx : mn;
                    }
                } else if (j == 2) {
#pragma unroll
                    for (int r = 0; r < 2; ++r) {
                        const int e = 4 * lane + r;
                        const bool desc = (e & k) == 0;
                        const unsigned long long a = S[r], c = S[r + 2];
                        const unsigned long long mx = a > c ? a : c;
                        const unsigned long long mn = a > c ? c : a;
                        S[r] = desc ? mx : mn;
                        S[r + 2] = desc ? mn : mx;
                    }
                } else {
#pragma unroll
                    for (int r = 0; r < 4; r += 2) {
                        const int e = 4 * lane + r;
                        const bool desc = (e & k) == 0;
                        const unsigned long long a = S[r], c = S[r + 1];
                        const unsigned long long mx = a > c ? a : c;
                        const unsigned long long mn = a > c ? c : a;
                        S[r] = desc ? mx : mn;
                        S[r + 1] = desc ? mn : mx;
                    }
                }
            }
        }
#pragma unroll
        for (int r = 0; r < 4; ++r) {
            const int e = 4 * lane + r;
            if (e < KSEL) idx_out[obase + e] = (int)(~(unsigned)S[r]);
        }
    } else {
        // cold exact fallback: bisection on 32-bit key, recompute from LDS
        auto keyf = [&](int j) -> unsigned {
            const float cx = sx[j], cy = sy[j], cz = sz[j];
            const float cxx = __fadd_rn(__fadd_rn(__fmul_rn(cx, cx), __fmul_rn(cy, cy)), __fmul_rn(cz, cz));
            const float dt  = __fadd_rn(__fadd_rn(__fmul_rn(qx, cx), __fmul_rn(qy, cy)), __fmul_rn(qz, cz));
            const float pd  = __fsub_rn(__fsub_rn(__fmul_rn(2.0f, dt), qxx), cxx);
            const unsigned u = __float_as_uint(pd);
            return u ^ ((unsigned)((int)u >> 31) | 0x80000000u);
        };
        unsigned P = 0;
        for (int bit = 31; bit >= 0; --bit) {
            const unsigned cand = P | (1u << bit);
            int c = 0;
            for (int t = 0; t < 64; ++t) c += (keyf(lane + (t << 6)) >= cand) ? 1 : 0;
            for (int o = 32; o > 0; o >>= 1) c += __shfl_xor(c, o, 64);
            if (c >= KSEL) P = cand;
        }
        int emitted = 0;
        for (int t = 0; t < 64; ++t) {
            const int j = lane + (t << 6);
            const bool g = keyf(j) > P;
            const unsigned long long m = __ballot(g);
            if (g) {
                const int pos = emitted + (int)__popcll(m & ((1ULL << lane) - 1ULL));
                idx_out[obase + pos] = j;
            }
            emitted += (int)__popcll(m);
        }
        for (int t = 0; t < 64 && emitted < KSEL; ++t) {
            const int j = lane + (t << 6);
            const bool eq = (keyf(j) == P);
            const unsigned long long m = __ballot(eq);
            const int before = (int)__popcll(m & ((1ULL << lane) - 1ULL));
            if (eq && (emitted + before) < KSEL) idx_out[obase + emitted + before] = j;
            emitted += (int)__popcll(m);
        }
    }
}

// ---------------------------------------------------------------------------
// Kernel 2: transpose x [B,C,N] -> xT [B,N,C]
// ---------------------------------------------------------------------------
__global__ __launch_bounds__(256) void transpose_k(const float* __restrict__ x,
                                                   float* __restrict__ xT) {
    const int r = blockIdx.x * 256 + threadIdx.x;
    const int c = r & 63;
    const int n = (r >> 6) & (NPTS - 1);
    const int b = r >> 18;
    xT[r] = x[((size_t)(b * NC + c)) * NPTS + n];
}

// ---------------------------------------------------------------------------
// Kernel 3: spherical features + layer-1 matmul + BN1 stats
// ---------------------------------------------------------------------------
__global__ __launch_bounds__(256) void feat_l1_k(const float* __restrict__ xloc,
                                                 const int* __restrict__ idx,
                                                 const float* __restrict__ W1,
                                                 float* __restrict__ y1,
                                                 float* __restrict__ acc) {
    const int r  = blockIdx.x * 256 + threadIdx.x;
    const int bn = r / KSEL;
    const int b  = bn >> 12;
    const int n  = bn & (NPTS - 1);
    const int j  = idx[r];

    const float* xb = xloc + (size_t)b * (3 * NPTS);
    const float cx = xb[n], cy = xb[NPTS + n], cz = xb[2 * NPTS + n];
    const float xr = xb[j] - cx;
    const float yr = xb[NPTS + j] - cy;
    const float zr = xb[2 * NPTS + j] - cz;

    const float sxy2 = xr * xr + yr * yr;
    const float r2   = sxy2 + zr * zr;
    const float rho  = sqrtf(fmaxf(r2, 1e-20f));
    const float sxy  = sqrtf(fmaxf(sxy2, 1e-20f));
    const bool dr = r2 < 1e-20f;
    const bool dp = sxy2 < 1e-20f;
    const float theta = atan2f(dr ? 0.0f : zr, dr ? 1.0f : sxy);
    const float phi   = atan2f(dp ? 0.0f : yr, dp ? 1.0f : xr);
    const float mean  = (rho + theta + phi) * (1.0f / 3.0f);

    float f[6] = {rho, theta, phi, rho - mean, theta - mean, phi - mean};
    float s[6], q[6];
#pragma unroll
    for (int c = 0; c < 6; ++c) {
        float a = 0.0f;
#pragma unroll
        for (int d = 0; d < 6; ++d) a = fmaf(W1[c * 6 + d], f[d], a);
        y1[(size_t)r * 6 + c] = a;
        s[c] = a;
        q[c] = a * a;
    }
#pragma unroll
    for (int o = 32; o > 0; o >>= 1) {
#pragma unroll
        for (int c = 0; c < 6; ++c) {
            s[c] += __shfl_xor(s[c], o, 64);
            q[c] += __shfl_xor(q[c], o, 64);
        }
    }
    __shared__ float red[4][12];
    const int lane = threadIdx.x & 63, wv = threadIdx.x >> 6;
    if (lane == 0) {
#pragma unroll
        for (int c = 0; c < 6; ++c) { red[wv][c] = s[c]; red[wv][6 + c] = q[c]; }
    }
    __syncthreads();
    if (threadIdx.x < 12) {
        const float vsum = red[0][threadIdx.x] + red[1][threadIdx.x] +
                           red[2][threadIdx.x] + red[3][threadIdx.x];
        atomicAdd(&acc[threadIdx.x * 64 + (blockIdx.x & 63)], vsum);
    }
}

// ---------------------------------------------------------------------------
// Kernel 4: BN1 + lrelu + layer-2 matmul + BN2 stats
// ---------------------------------------------------------------------------
__global__ __launch_bounds__(256) void mlp2_k(const float* __restrict__ y1,
                                              const float* __restrict__ W2,
                                              const float* __restrict__ g1,
                                              const float* __restrict__ b1,
                                              const float* __restrict__ acc1,
                                              float* __restrict__ y2,
                                              float* __restrict__ acc2) {
    __shared__ float sraw[12];
    __shared__ float sS[6], sT[6];
    if (threadIdx.x < 12) {
        float v = 0.0f;
        const float* p = acc1 + threadIdx.x * 64;
#pragma unroll
        for (int i = 0; i < 64; ++i) v += p[i];
        sraw[threadIdx.x] = v;
    }
    __syncthreads();
    if (threadIdx.x < 6) {
        const float inv = 1.0f / CNT_F;
        const float mu  = sraw[threadIdx.x] * inv;
        const float var = sraw[6 + threadIdx.x] * inv - mu * mu;
        const float sc  = g1[threadIdx.x] / sqrtf(var + 1e-5f);
        sS[threadIdx.x] = sc;
        sT[threadIdx.x] = b1[threadIdx.x] - mu * sc;
    }
    __syncthreads();

    const int r = blockIdx.x * 256 + threadIdx.x;
    float h[6];
#pragma unroll
    for (int c = 0; c < 6; ++c) {
        const float z = fmaf(y1[(size_t)r * 6 + c], sS[c], sT[c]);
        h[c] = z >= 0.0f ? z : 0.2f * z;
    }
    float s[3], q[3];
#pragma unroll
    for (int c = 0; c < 3; ++c) {
        float a = 0.0f;
#pragma unroll
        for (int d = 0; d < 6; ++d) a = fmaf(W2[c * 6 + d], h[d], a);
        y2[(size_t)r * 3 + c] = a;
        s[c] = a;
        q[c] = a * a;
    }
#pragma unroll
    for (int o = 32; o > 0; o >>= 1) {
#pragma unroll
        for (int c = 0; c < 3; ++c) {
            s[c] += __shfl_xor(s[c], o, 64);
            q[c] += __shfl_xor(q[c], o, 64);
        }
    }
    __shared__ float red[4][6];
    const int lane = threadIdx.x & 63, wv = threadIdx.x >> 6;
    if (lane == 0) {
#pragma unroll
        for (int c = 0; c < 3; ++c) { red[wv][c] = s[c]; red[wv][3 + c] = q[c]; }
    }
    __syncthreads();
    if (threadIdx.x < 6) {
        const float v = red[0][threadIdx.x] + red[1][threadIdx.x] +
                        red[2][threadIdx.x] + red[3][threadIdx.x];
        atomicAdd(&acc2[threadIdx.x * 64 + (blockIdx.x & 63)], v);
    }
}

// ---------------------------------------------------------------------------
// Kernel 5: BN2 + lrelu + layer-3 matmul + BN3 stats
// ---------------------------------------------------------------------------
__global__ __launch_bounds__(256) void mlp3_k(const float* __restrict__ y2,
                                              const float* __restrict__ W3,
                                              const float* __restrict__ g2,
                                              const float* __restrict__ b2,
                                              const float* __restrict__ acc2,
                                              float* __restrict__ y3,
                                              float* __restrict__ acc3) {
    __shared__ float sraw[6];
    __shared__ float sS[3], sT[3];
    if (threadIdx.x < 6) {
        float v = 0.0f;
        const float* p = acc2 + threadIdx.x * 64;
#pragma unroll
        for (int i = 0; i < 64; ++i) v += p[i];
        sraw[threadIdx.x] = v;
    }
    __syncthreads();
    if (threadIdx.x < 3) {
        const float inv = 1.0f / CNT_F;
        const float mu  = sraw[threadIdx.x] * inv;
        const float var = sraw[3 + threadIdx.x] * inv - mu * mu;
        const float sc  = g2[threadIdx.x] / sqrtf(var + 1e-5f);
        sS[threadIdx.x] = sc;
        sT[threadIdx.x] = b2[threadIdx.x] - mu * sc;
    }
    __syncthreads();

    const int r = blockIdx.x * 256 + threadIdx.x;
    float h[3];
#pragma unroll
    for (int c = 0; c < 3; ++c) {
        const float z = fmaf(y2[(size_t)r * 3 + c], sS[c], sT[c]);
        h[c] = z >= 0.0f ? z : 0.2f * z;
    }
    float a = 0.0f;
#pragma unroll
    for (int d = 0; d < 3; ++d) a = fmaf(W3[d], h[d], a);
    y3[r] = a;

    float s = a, q = a * a;
#pragma unroll
    for (int o = 32; o > 0; o >>= 1) {
        s += __shfl_xor(s, o, 64);
        q += __shfl_xor(q, o, 64);
    }
    __shared__ float red[4][2];
    const int lane = threadIdx.x & 63, wv = threadIdx.x >> 6;
    if (lane == 0) { red[wv][0] = s; red[wv][1] = q; }
    __syncthreads();
    if (threadIdx.x < 2) {
        const float v = red[0][threadIdx.x] + red[1][threadIdx.x] +
                        red[2][threadIdx.x] + red[3][threadIdx.x];
        atomicAdd(&acc3[threadIdx.x * 64 + (blockIdx.x & 63)], v);
    }
}

// ---------------------------------------------------------------------------
// Kernel 6: BN3 + lrelu + softmax over k + gather/aggregate + residual out
// one wave per (b,n); lane = channel
// ---------------------------------------------------------------------------
__global__ __launch_bounds__(256) void attn_out_k(const float* __restrict__ y3,
                                                  const int* __restrict__ idx,
                                                  const float* __restrict__ xT,
                                                  const float* __restrict__ g3,
                                                  const float* __restrict__ b3,
                                                  const float* __restrict__ acc3,
                                                  float* __restrict__ out) {
    __shared__ float sst[2];
    if (threadIdx.x < 2) {
        float v = 0.0f;
        const float* p = acc3 + threadIdx.x * 64;
#pragma unroll
        for (int i = 0; i < 64; ++i) v += p[i];
        sst[threadIdx.x] = v;
    }
    __syncthreads();
    const float inv = 1.0f / CNT_F;
    const float mu  = sst[0] * inv;
    const float var = sst[1] * inv - mu * mu;
    const float sc  = g3[0] / sqrtf(var + 1e-5f);
    const float tb  = b3[0] - mu * sc;

    const int lane = threadIdx.x & 63, wv = threadIdx.x >> 6;
    const int bn = blockIdx.x * 4 + wv;
    const int b  = bn >> 12;
    const int n  = bn & (NPTS - 1);

    float att = 0.0f;
    int j = 0;
    if (lane < KSEL) {
        const float z = fmaf(y3[(size_t)bn * KSEL + lane], sc, tb);
        att = z >= 0.0f ? z : 0.2f * z;
        j = idx[(size_t)bn * KSEL + lane];
    }
    float m = (lane < KSEL) ? att : -3.0e38f;
#pragma unroll
    for (int o = 32; o > 0; o >>= 1) m = fmaxf(m, __shfl_xor(m, o, 64));
    const float e = (lane < KSEL) ? expf(att - m) : 0.0f;
    float ssum = e;
#pragma unroll
    for (int o = 32; o > 0; o >>= 1) ssum += __shfl_xor(ssum, o, 64);
    const float w = e / ssum;

    const float* xTb = xT + ((size_t)b << 18);  // b * N * C
    float accv = 0.0f;
    for (int t = 0; t < KSEL; ++t) {
        const int   jt = __shfl(j, t, 64);
        const float at = __shfl(w, t, 64);
        accv = fmaf(at, xTb[((size_t)jt << 6) + lane], accv);
    }
    const float xv = xTb[((size_t)n << 6) + lane];
    out[((size_t)(b * NC + lane)) * NPTS + n] = xv + accv;
}

// ---------------------------------------------------------------------------
extern "C" void kernel_launch(void* const* d_in, const int* in_sizes, int n_in,
                              void* d_out, int out_size, void* d_ws, size_t ws_size,
                              hipStream_t stream) {
    const float* x_loc = (const float*)d_in[0];
    const float* x     = (const float*)d_in[1];
    const float* W1    = (const float*)d_in[2];
    const float* g1    = (const float*)d_in[3];
    const float* b1    = (const float*)d_in[4];
    const float* W2    = (const float*)d_in[5];
    const float* g2    = (const float*)d_in[6];
    const float* b2    = (const float*)d_in[7];
    const float* W3    = (const float*)d_in[8];
    const float* g3    = (const float*)d_in[9];
    const float* b3    = (const float*)d_in[10];
    float* out = (float*)d_out;

    char* ws = (char*)d_ws;
    float* acc  = (float*)ws;                               // 2048 floats (8KB), zeroed
    int*   idx  = (int*)(ws + 8192);                        // 983040 ints
    float* y1   = (float*)(ws + 8192 + 3932160);            // 983040*6
    float* y2   = (float*)(ws + 8192 + 3932160 + 23592960); // 983040*3
    float* y3   = (float*)(ws + 8192 + 3932160 + 23592960 + 11796480);           // 983040
    float* xT   = (float*)(ws + 8192 + 3932160 + 23592960 + 11796480 + 3932160); // 2097152

    float* acc1 = acc;          // 12 ch * 64 slots
    float* acc2 = acc + 768;    //  6 * 64
    float* acc3 = acc + 1152;   //  2 * 64

    hipMemsetAsync(acc, 0, 8192, stream);

    knn_k<<<dim3(NPTS / 4, NB), 256, 0, stream>>>(x_loc, idx);
    transpose_k<<<(NB * NC * NPTS) / 256, 256, 0, stream>>>(x, xT);
    feat_l1_k<<<NROWS / 256, 256, 0, stream>>>(x_loc, idx, W1, y1, acc1);
    mlp2_k<<<NROWS / 256, 256, 0, stream>>>(y1, W2, g1, b1, acc1, y2, acc2);
    mlp3_k<<<NROWS / 256, 256, 0, stream>>>(y2, W3, g2, b2, acc2, y3, acc3);
    attn_out_k<<<(NB * NPTS) / 4, 256, 0, stream>>>(y3, idx, xT, g3, b3, acc3, out);
}

// Round 2
// 290.138 us; speedup vs baseline: 1.3716x; 1.3716x over previous
//
#include <hip/hip_runtime.h>
#include <math.h>

#define NPTS 4096
#define NB   8
#define NC   64
#define KSEL 30
#define NROWS (NB * NPTS * KSEL)   // 983040
#define CNT_F 983040.0f

static __device__ __forceinline__ unsigned long long shfl_xor_u64(unsigned long long v, int lx) {
    int lo = __shfl_xor((int)(unsigned)(v & 0xFFFFFFFFULL), lx, 64);
    int hi = __shfl_xor((int)(unsigned)(v >> 32), lx, 64);
    return ((unsigned long long)(unsigned)hi << 32) | (unsigned)lo;
}

// ---------------------------------------------------------------------------
// Kernel 0: pack [x,y,z,xx] per point (xx with numpy-strict rounding)
// ---------------------------------------------------------------------------
__global__ __launch_bounds__(256) void prep_k(const float* __restrict__ xloc,
                                              float4* __restrict__ pts4) {
    const int i = blockIdx.x * 256 + threadIdx.x;  // over B*N = 32768
    const int b = i >> 12;
    const int n = i & (NPTS - 1);
    const float* xb = xloc + (size_t)b * (3 * NPTS);
    const float x = xb[n], y = xb[NPTS + n], z = xb[2 * NPTS + n];
    const float xx = __fadd_rn(__fadd_rn(__fmul_rn(x, x), __fmul_rn(y, y)), __fmul_rn(z, z));
    pts4[i] = make_float4(x, y, z, xx);
}

// ---------------------------------------------------------------------------
// Kernel 1: exact KNN. 8 queries/block (one per wave), pts4 staged in 64KB LDS.
// Survivor buffer reuses the pts LDS region after a __syncthreads.
// ---------------------------------------------------------------------------
__global__ __launch_bounds__(512, 4) void knn_k(const float4* __restrict__ pts4g,
                                                int* __restrict__ idx_out) {
    __shared__ float4 pts[NPTS];   // exactly 64KB

    const int tid  = threadIdx.x;
    const int lane = tid & 63;
    const int wv   = tid >> 6;
    const int b    = blockIdx.y;
    const int n    = (blockIdx.x << 3) + wv;

    const float4* pg = pts4g + ((size_t)b << 12);
    for (int i = tid; i < NPTS; i += 512) pts[i] = pg[i];
    __syncthreads();

    const float4 q = pts[n];

    unsigned K[64];
    unsigned lm = 0;
#pragma unroll
    for (int t = 0; t < 64; ++t) {
        const float4 c = pts[lane + (t << 6)];
        const float dt = __fadd_rn(__fadd_rn(__fmul_rn(q.x, c.x), __fmul_rn(q.y, c.y)), __fmul_rn(q.z, c.z));
        const float pd = __fsub_rn(__fsub_rn(__fmul_rn(2.0f, dt), q.w), c.w);
        const unsigned u = __float_as_uint(pd);
        const unsigned key = u ^ ((unsigned)((int)u >> 31) | 0x80000000u);
        K[t] = key;
        lm = key > lm ? key : lm;
    }

    // bitonic sort of 64 lane-maxima (descending); tau = 31st largest
    unsigned v = lm;
#pragma unroll
    for (int k = 2; k <= 64; k <<= 1) {
#pragma unroll
        for (int j = k >> 1; j > 0; j >>= 1) {
            const unsigned o = (unsigned)__shfl_xor((int)v, j, 64);
            const bool keepmax = ((lane & j) == 0) == ((lane & k) == 0);
            const unsigned mx = v > o ? v : o;
            const unsigned mn = v > o ? o : v;
            v = keepmax ? mx : mn;
        }
    }
    const unsigned tau = (unsigned)__shfl((int)v, 30, 64);

    __syncthreads();  // everyone done reading pts -> safe to reuse as surv

    unsigned long long* surv = ((unsigned long long*)pts) + (wv << 6);
    surv[lane] = 0ULL;

    unsigned total = 0;
#pragma unroll
    for (int t = 0; t < 64; ++t) {
        const bool p = (K[t] >= tau);
        const unsigned long long m = __ballot(p);
        if (p) {
            const unsigned pos = total + (unsigned)__popcll(m & ((1ULL << lane) - 1ULL));
            if (pos < 64u) {
                const unsigned j = (unsigned)(lane + (t << 6));
                surv[pos] = ((unsigned long long)K[t] << 32) | (unsigned)(~j);
            }
        }
        total += (unsigned)__popcll(m);
    }
    __threadfence_block();

    const size_t obase = ((size_t)((b << 12) + n)) * KSEL;

    if (total <= 64u) {
        // one-per-lane 64-element bitonic sort (descending) of packed (key,~j)
        unsigned long long s = surv[lane];
#pragma unroll
        for (int k = 2; k <= 64; k <<= 1) {
#pragma unroll
            for (int j = k >> 1; j > 0; j >>= 1) {
                const unsigned long long o = shfl_xor_u64(s, j);
                const bool keepmax = ((lane & j) == 0) == ((lane & k) == 0);
                const unsigned long long mx = s > o ? s : o;
                const unsigned long long mn = s > o ? o : s;
                s = keepmax ? mx : mn;
            }
        }
        if (lane < KSEL) idx_out[obase + lane] = (int)(~(unsigned)s);
    } else {
        // rare exact fallback: 32-bit bisection on in-register keys
        unsigned P = 0;
        for (int bit = 31; bit >= 0; --bit) {
            const unsigned cand = P | (1u << bit);
            int c = 0;
#pragma unroll
            for (int t = 0; t < 64; ++t) c += (K[t] >= cand) ? 1 : 0;
#pragma unroll
            for (int o = 32; o > 0; o >>= 1) c += __shfl_xor(c, o, 64);
            if (c >= KSEL) P = cand;
        }
        int emitted = 0;
#pragma unroll
        for (int t = 0; t < 64; ++t) {
            const bool g = (K[t] > P);
            const unsigned long long m = __ballot(g);
            if (g) {
                const int pos = emitted + (int)__popcll(m & ((1ULL << lane) - 1ULL));
                idx_out[obase + pos] = lane + (t << 6);
            }
            emitted += (int)__popcll(m);
        }
#pragma unroll
        for (int t = 0; t < 64; ++t) {
            const bool e_ = (K[t] == P);
            const unsigned long long m = __ballot(e_);
            const int before = (int)__popcll(m & ((1ULL << lane) - 1ULL));
            if (e_ && (emitted + before) < KSEL) idx_out[obase + emitted + before] = lane + (t << 6);
            emitted += (int)__popcll(m);
        }
    }
}

// ---------------------------------------------------------------------------
// Kernel 2: tiled transpose x [B,C,N] -> xT [B,N,C], coalesced both sides
// ---------------------------------------------------------------------------
__global__ __launch_bounds__(256) void transpose_k(const float* __restrict__ x,
                                                   float* __restrict__ xT) {
    __shared__ float tile[64][65];
    const int b  = blockIdx.y;
    const int n0 = blockIdx.x << 6;
    const int tx = threadIdx.x & 63;
    const int ty = threadIdx.x >> 6;  // 0..3
    const float* xb = x + ((size_t)b << 18);
#pragma unroll
    for (int i = 0; i < 16; ++i) {
        const int c = (i << 2) + ty;
        tile[c][tx] = xb[((size_t)c << 12) + n0 + tx];
    }
    __syncthreads();
    float* ob = xT + ((size_t)b << 18);
#pragma unroll
    for (int i = 0; i < 16; ++i) {
        const int nl = (i << 2) + ty;
        ob[((size_t)(n0 + nl) << 6) + tx] = tile[tx][nl];
    }
}

// ---------------------------------------------------------------------------
// Kernel 3: spherical features + layer-1 matmul + BN1 stats (y1 planar [6][NROWS])
// ---------------------------------------------------------------------------
__global__ __launch_bounds__(256) void feat_l1_k(const float4* __restrict__ pts4,
                                                 const int* __restrict__ idx,
                                                 const float* __restrict__ W1,
                                                 float* __restrict__ y1,
                                                 float* __restrict__ acc) {
    const int r  = blockIdx.x * 256 + threadIdx.x;
    const int bn = r / KSEL;
    const int b  = bn >> 12;
    const int j  = idx[r];

    const float4 ctr = pts4[bn];
    const float4 nb  = pts4[(b << 12) + j];
    const float xr = nb.x - ctr.x;
    const float yr = nb.y - ctr.y;
    const float zr = nb.z - ctr.z;

    const float sxy2 = xr * xr + yr * yr;
    const float r2   = sxy2 + zr * zr;
    const float rho  = sqrtf(fmaxf(r2, 1e-20f));
    const float sxy  = sqrtf(fmaxf(sxy2, 1e-20f));
    const bool dr = r2 < 1e-20f;
    const bool dp = sxy2 < 1e-20f;
    const float theta = atan2f(dr ? 0.0f : zr, dr ? 1.0f : sxy);
    const float phi   = atan2f(dp ? 0.0f : yr, dp ? 1.0f : xr);
    const float mean  = (rho + theta + phi) * (1.0f / 3.0f);

    float f[6] = {rho, theta, phi, rho - mean, theta - mean, phi - mean};
    float s[6], qq[6];
#pragma unroll
    for (int c = 0; c < 6; ++c) {
        float a = 0.0f;
#pragma unroll
        for (int d = 0; d < 6; ++d) a = fmaf(W1[c * 6 + d], f[d], a);
        y1[(size_t)c * NROWS + r] = a;
        s[c] = a;
        qq[c] = a * a;
    }
#pragma unroll
    for (int o = 32; o > 0; o >>= 1) {
#pragma unroll
        for (int c = 0; c < 6; ++c) {
            s[c]  += __shfl_xor(s[c], o, 64);
            qq[c] += __shfl_xor(qq[c], o, 64);
        }
    }
    __shared__ float red[4][12];
    const int lane = threadIdx.x & 63, wv = threadIdx.x >> 6;
    if (lane == 0) {
#pragma unroll
        for (int c = 0; c < 6; ++c) { red[wv][c] = s[c]; red[wv][6 + c] = qq[c]; }
    }
    __syncthreads();
    if (threadIdx.x < 12) {
        const float vsum = red[0][threadIdx.x] + red[1][threadIdx.x] +
                           red[2][threadIdx.x] + red[3][threadIdx.x];
        atomicAdd(&acc[threadIdx.x * 64 + (blockIdx.x & 63)], vsum);
    }
}

// ---------------------------------------------------------------------------
// Kernel 4: BN1 + lrelu + layer-2 matmul + BN2 stats (planar y1 -> planar y2)
// ---------------------------------------------------------------------------
__global__ __launch_bounds__(256) void mlp2_k(const float* __restrict__ y1,
                                              const float* __restrict__ W2,
                                              const float* __restrict__ g1,
                                              const float* __restrict__ b1,
                                              const float* __restrict__ acc1,
                                              float* __restrict__ y2,
                                              float* __restrict__ acc2) {
    __shared__ float sraw[12];
    __shared__ float sS[6], sT[6];
    if (threadIdx.x < 12) {
        float v = 0.0f;
        const float* p = acc1 + threadIdx.x * 64;
#pragma unroll
        for (int i = 0; i < 64; ++i) v += p[i];
        sraw[threadIdx.x] = v;
    }
    __syncthreads();
    if (threadIdx.x < 6) {
        const float inv = 1.0f / CNT_F;
        const float mu  = sraw[threadIdx.x] * inv;
        const float var = sraw[6 + threadIdx.x] * inv - mu * mu;
        const float sc  = g1[threadIdx.x] / sqrtf(var + 1e-5f);
        sS[threadIdx.x] = sc;
        sT[threadIdx.x] = b1[threadIdx.x] - mu * sc;
    }
    __syncthreads();

    const int r = blockIdx.x * 256 + threadIdx.x;
    float h[6];
#pragma unroll
    for (int c = 0; c < 6; ++c) {
        const float z = fmaf(y1[(size_t)c * NROWS + r], sS[c], sT[c]);
        h[c] = z >= 0.0f ? z : 0.2f * z;
    }
    float s[3], q[3];
#pragma unroll
    for (int c = 0; c < 3; ++c) {
        float a = 0.0f;
#pragma unroll
        for (int d = 0; d < 6; ++d) a = fmaf(W2[c * 6 + d], h[d], a);
        y2[(size_t)c * NROWS + r] = a;
        s[c] = a;
        q[c] = a * a;
    }
#pragma unroll
    for (int o = 32; o > 0; o >>= 1) {
#pragma unroll
        for (int c = 0; c < 3; ++c) {
            s[c] += __shfl_xor(s[c], o, 64);
            q[c] += __shfl_xor(q[c], o, 64);
        }
    }
    __shared__ float red[4][6];
    const int lane = threadIdx.x & 63, wv = threadIdx.x >> 6;
    if (lane == 0) {
#pragma unroll
        for (int c = 0; c < 3; ++c) { red[wv][c] = s[c]; red[wv][3 + c] = q[c]; }
    }
    __syncthreads();
    if (threadIdx.x < 6) {
        const float v = red[0][threadIdx.x] + red[1][threadIdx.x] +
                        red[2][threadIdx.x] + red[3][threadIdx.x];
        atomicAdd(&acc2[threadIdx.x * 64 + (blockIdx.x & 63)], v);
    }
}

// ---------------------------------------------------------------------------
// Kernel 5: BN2 + lrelu + layer-3 matmul + BN3 stats
// ---------------------------------------------------------------------------
__global__ __launch_bounds__(256) void mlp3_k(const float* __restrict__ y2,
                                              const float* __restrict__ W3,
                                              const float* __restrict__ g2,
                                              const float* __restrict__ b2,
                                              const float* __restrict__ acc2,
                                              float* __restrict__ y3,
                                              float* __restrict__ acc3) {
    __shared__ float sraw[6];
    __shared__ float sS[3], sT[3];
    if (threadIdx.x < 6) {
        float v = 0.0f;
        const float* p = acc2 + threadIdx.x * 64;
#pragma unroll
        for (int i = 0; i < 64; ++i) v += p[i];
        sraw[threadIdx.x] = v;
    }
    __syncthreads();
    if (threadIdx.x < 3) {
        const float inv = 1.0f / CNT_F;
        const float mu  = sraw[threadIdx.x] * inv;
        const float var = sraw[3 + threadIdx.x] * inv - mu * mu;
        const float sc  = g2[threadIdx.x] / sqrtf(var + 1e-5f);
        sS[threadIdx.x] = sc;
        sT[threadIdx.x] = b2[threadIdx.x] - mu * sc;
    }
    __syncthreads();

    const int r = blockIdx.x * 256 + threadIdx.x;
    float h[3];
#pragma unroll
    for (int c = 0; c < 3; ++c) {
        const float z = fmaf(y2[(size_t)c * NROWS + r], sS[c], sT[c]);
        h[c] = z >= 0.0f ? z : 0.2f * z;
    }
    float a = 0.0f;
#pragma unroll
    for (int d = 0; d < 3; ++d) a = fmaf(W3[d], h[d], a);
    y3[r] = a;

    float s = a, q = a * a;
#pragma unroll
    for (int o = 32; o > 0; o >>= 1) {
        s += __shfl_xor(s, o, 64);
        q += __shfl_xor(q, o, 64);
    }
    __shared__ float red[4][2];
    const int lane = threadIdx.x & 63, wv = threadIdx.x >> 6;
    if (lane == 0) { red[wv][0] = s; red[wv][1] = q; }
    __syncthreads();
    if (threadIdx.x < 2) {
        const float v = red[0][threadIdx.x] + red[1][threadIdx.x] +
                        red[2][threadIdx.x] + red[3][threadIdx.x];
        atomicAdd(&acc3[threadIdx.x * 64 + (blockIdx.x & 63)], v);
    }
}

// ---------------------------------------------------------------------------
// Kernel 6: BN3 + lrelu + softmax over k + gather/aggregate + residual out
// ---------------------------------------------------------------------------
__global__ __launch_bounds__(256) void attn_out_k(const float* __restrict__ y3,
                                                  const int* __restrict__ idx,
                                                  const float* __restrict__ xT,
                                                  const float* __restrict__ g3,
                                                  const float* __restrict__ b3,
                                                  const float* __restrict__ acc3,
                                                  float* __restrict__ out) {
    __shared__ float sst[2];
    if (threadIdx.x < 2) {
        float v = 0.0f;
        const float* p = acc3 + threadIdx.x * 64;
#pragma unroll
        for (int i = 0; i < 64; ++i) v += p[i];
        sst[threadIdx.x] = v;
    }
    __syncthreads();
    const float inv = 1.0f / CNT_F;
    const float mu  = sst[0] * inv;
    const float var = sst[1] * inv - mu * mu;
    const float sc  = g3[0] / sqrtf(var + 1e-5f);
    const float tb  = b3[0] - mu * sc;

    const int lane = threadIdx.x & 63, wv = threadIdx.x >> 6;
    const int bn = blockIdx.x * 4 + wv;
    const int b  = bn >> 12;
    const int n  = bn & (NPTS - 1);

    float att = 0.0f;
    int j = 0;
    if (lane < KSEL) {
        const float z = fmaf(y3[(size_t)bn * KSEL + lane], sc, tb);
        att = z >= 0.0f ? z : 0.2f * z;
        j = idx[(size_t)bn * KSEL + lane];
    }
    float m = (lane < KSEL) ? att : -3.0e38f;
#pragma unroll
    for (int o = 32; o > 0; o >>= 1) m = fmaxf(m, __shfl_xor(m, o, 64));
    const float e = (lane < KSEL) ? expf(att - m) : 0.0f;
    float ssum = e;
#pragma unroll
    for (int o = 32; o > 0; o >>= 1) ssum += __shfl_xor(ssum, o, 64);
    const float w = e / ssum;

    const float* xTb = xT + ((size_t)b << 18);
    float accv = 0.0f;
    for (int t = 0; t < KSEL; ++t) {
        const int   jt = __shfl(j, t, 64);
        const float at = __shfl(w, t, 64);
        accv = fmaf(at, xTb[((size_t)jt << 6) + lane], accv);
    }
    const float xv = xTb[((size_t)n << 6) + lane];
    out[((size_t)(b * NC + lane)) * NPTS + n] = xv + accv;
}

// ---------------------------------------------------------------------------
extern "C" void kernel_launch(void* const* d_in, const int* in_sizes, int n_in,
                              void* d_out, int out_size, void* d_ws, size_t ws_size,
                              hipStream_t stream) {
    const float* x_loc = (const float*)d_in[0];
    const float* x     = (const float*)d_in[1];
    const float* W1    = (const float*)d_in[2];
    const float* g1    = (const float*)d_in[3];
    const float* b1    = (const float*)d_in[4];
    const float* W2    = (const float*)d_in[5];
    const float* g2    = (const float*)d_in[6];
    const float* b2    = (const float*)d_in[7];
    const float* W3    = (const float*)d_in[8];
    const float* g3    = (const float*)d_in[9];
    const float* b3    = (const float*)d_in[10];
    float* out = (float*)d_out;

    float*  acc  = (float*)d_ws;              // 2048 floats, zeroed below
    float4* pts4 = (float4*)(acc + 2048);     // 32768 float4
    int*    idx  = (int*)(pts4 + 32768);      // 983040 ints
    float*  y1   = (float*)(idx + NROWS);     // 6 * NROWS (planar)
    float*  y2   = y1 + 6 * (size_t)NROWS;    // 3 * NROWS (planar)
    float*  y3   = y2 + 3 * (size_t)NROWS;    // NROWS
    float*  xT   = y3 + (size_t)NROWS;        // B*N*C = 2097152

    float* acc1 = acc;          // 12 ch * 64 slots
    float* acc2 = acc + 768;    //  6 * 64
    float* acc3 = acc + 1152;   //  2 * 64

    hipMemsetAsync(acc, 0, 8192, stream);

    prep_k<<<(NB * NPTS) / 256, 256, 0, stream>>>(x_loc, pts4);
    knn_k<<<dim3(NPTS / 8, NB), 512, 0, stream>>>(pts4, idx);
    transpose_k<<<dim3(NPTS / 64, NB), 256, 0, stream>>>(x, xT);
    feat_l1_k<<<NROWS / 256, 256, 0, stream>>>(pts4, idx, W1, y1, acc1);
    mlp2_k<<<NROWS / 256, 256, 0, stream>>>(y1, W2, g1, b1, acc1, y2, acc2);
    mlp3_k<<<NROWS / 256, 256, 0, stream>>>(y2, W3, g2, b2, acc2, y3, acc3);
    attn_out_k<<<(NB * NPTS) / 4, 256, 0, stream>>>(y3, idx, xT, g3, b3, acc3, out);
}